// Round 14
// baseline (245.428 us; speedup 1.0000x reference)
//
#include <hip/hip_runtime.h>
#include <stdint.h>

// ---------------------------------------------------------------------------
// Bucketed linear attention, round 13: R12 + GEMM K-loop rebuilt as the
// 8-phase template with stage-lead-2: tile t's 4 phases stage
// {A-kh1(t+1), B-kh1(t+1), A-kh0(t+2), B-kh0(t+2)} (1 half/phase), one
// vmcnt(4) gate per tile (at P4). Phases = (kk, mh), 16 MFMA each,
// {ds_reads; stage; barrier; lgkmcnt(0); setprio MFMA; barrier}.
// Ledger (induction): at t's P4 gate vmcnt(4) leaves only kh0(t+2) in
// flight => ALL tile-t+1 halves landed. P3/P4 stages write cur-buf kh0,
// whose reads completed at P2's barrier (race-free by barrier).
//   ws layout (~177 MB): as R12.
// ---------------------------------------------------------------------------

typedef unsigned short u16;
typedef unsigned int u32;
typedef u16   u16x4  __attribute__((ext_vector_type(4)));
typedef u16   u16x8  __attribute__((ext_vector_type(8)));
typedef float f32x4  __attribute__((ext_vector_type(4)));
typedef float float4v __attribute__((ext_vector_type(4)));
typedef __bf16 bf16x8 __attribute__((ext_vector_type(8)));

__device__ __forceinline__ u16 f2bf(float f) {
  return __builtin_bit_cast(u16, (__bf16)f);
}
__device__ __forceinline__ float bf2f(u16 h) {
  return (float)__builtin_bit_cast(__bf16, h);
}

__device__ __forceinline__ void stage16(const u16* g, u16* l) {
  __builtin_amdgcn_global_load_lds(
      (const __attribute__((address_space(1))) u32*)g,
      (__attribute__((address_space(3))) u32*)l, 16, 0, 0);
}

// ------------- fp32 -> bf16 convert (all 3 inputs, 8 elem/thread) -----------
// ranges (u16x8 units): x 2097152 | qkv_w 393216 | proj_w 131072
__global__ __launch_bounds__(256) void cvt_all(
    const float* __restrict__ x, const float* __restrict__ wqf,
    const float* __restrict__ wpf, u16* __restrict__ xb,
    u16* __restrict__ wq, u16* __restrict__ wp) {
  int i = blockIdx.x * 256 + threadIdx.x;
  const float* in; u16* out; int j;
  if (i < 2097152)      { in = x;   out = xb; j = i; }
  else if (i < 2490368) { in = wqf; out = wq; j = i - 2097152; }
  else                  { in = wpf; out = wp; j = i - 2490368; }
  float4v v0 = reinterpret_cast<const float4v*>(in)[j * 2];
  float4v v1 = reinterpret_cast<const float4v*>(in)[j * 2 + 1];
  u16x8 o;
  o[0] = f2bf(v0.x); o[1] = f2bf(v0.y); o[2] = f2bf(v0.z); o[3] = f2bf(v0.w);
  o[4] = f2bf(v1.x); o[5] = f2bf(v1.y); o[6] = f2bf(v1.z); o[7] = f2bf(v1.w);
  reinterpret_cast<u16x8*>(out)[j] = o;
}

// ------------- 256x256 NT bf16 MFMA GEMM (8-phase, stage-lead-2) ------------
// EPI=0: float C + bias (proj). EPI=2: fused feature maps ->
//   bn 0-3: softmax_e(q)*e^-0.5 -> Qf[bkt][n][e]
//   bn 4-7: exp(k) -> Kt[bkt][d][n] (u16x4) + ksum[bkt][d] (f32 partials)
//   bn 8-11: v     -> Vt[bkt][e][n] (u16x4)
template <int EPI>
__global__ __launch_bounds__(512, 2) void gemm256(
    const u16* __restrict__ A,      // [M][K] bf16
    const u16* __restrict__ B,      // [N][K] bf16
    const float* __restrict__ bias, // [N] (EPI==0)
    float* __restrict__ Cf,         // (EPI==0)
    u16* __restrict__ Qf, u16* __restrict__ Kt, u16* __restrict__ Vt,
    float* __restrict__ ksum,
    int N, int K, int NT) {         // NT = K/64
  __shared__ u16 As[2][2][256][32];
  __shared__ u16 Bs[2][2][256][32];
  const int tid = threadIdx.x, lane = tid & 63, wave = tid >> 6;
  const int wm = wave >> 2, wn = wave & 3;
  const int l15 = lane & 15, l4 = lane >> 4;
  const int ntn = N >> 8;
  const int cpx = gridDim.x >> 3;
  const int bid = (blockIdx.x & 7) * cpx + (blockIdx.x >> 3);
  const int bm = bid / ntn, bn = bid % ntn;

  const int srow = tid >> 2;
  const int gsl8 = ((tid & 3) ^ ((tid >> 3) & 3)) * 8;
  const u16* Ag = A + (size_t)(bm * 256 + srow) * K + gsl8;
  const u16* Bg = B + (size_t)(bn * 256 + srow) * K + gsl8;
  const size_t rj = (size_t)128 * K;
  const int slotr = (l4 ^ ((l15 >> 1) & 3)) * 8;

  f32x4 acc[8][4] = {};
  bf16x8 a0, a1, a2, a3, b0, b1, b2, b3;

#define STG(P, buf, kh, kt)                                        \
  { const u16* g_ = P##g + (kt) + (kh) * 32;                       \
    stage16(g_,      &P##s[buf][kh][wave * 16][0]);                \
    stage16(g_ + rj, &P##s[buf][kh][128 + wave * 16][0]); }

#define LDA4(kk, mh)                                                     \
  { const u16* p_ = &As[cur][kk][wm * 128 + (mh) * 64 + l15][0] + slotr; \
    a0 = *(const bf16x8*)(p_);                                           \
    a1 = *(const bf16x8*)(p_ + 512);                                     \
    a2 = *(const bf16x8*)(p_ + 1024);                                    \
    a3 = *(const bf16x8*)(p_ + 1536); }

#define LDB4(kk)                                                   \
  { const u16* p_ = &Bs[cur][kk][wn * 64 + l15][0] + slotr;        \
    b0 = *(const bf16x8*)(p_);                                     \
    b1 = *(const bf16x8*)(p_ + 512);                               \
    b2 = *(const bf16x8*)(p_ + 1024);                              \
    b3 = *(const bf16x8*)(p_ + 1536); }

#define MM(x, y, z) z = __builtin_amdgcn_mfma_f32_16x16x32_bf16(x, y, z, 0, 0, 0)
#define MFMA16(mb)                                                 \
  __builtin_amdgcn_s_setprio(1);                                   \
  MM(a0, b0, acc[(mb) + 0][0]); MM(a0, b1, acc[(mb) + 0][1]);      \
  MM(a0, b2, acc[(mb) + 0][2]); MM(a0, b3, acc[(mb) + 0][3]);      \
  MM(a1, b0, acc[(mb) + 1][0]); MM(a1, b1, acc[(mb) + 1][1]);      \
  MM(a1, b2, acc[(mb) + 1][2]); MM(a1, b3, acc[(mb) + 1][3]);      \
  MM(a2, b0, acc[(mb) + 2][0]); MM(a2, b1, acc[(mb) + 2][1]);      \
  MM(a2, b2, acc[(mb) + 2][2]); MM(a2, b3, acc[(mb) + 2][3]);      \
  MM(a3, b0, acc[(mb) + 3][0]); MM(a3, b1, acc[(mb) + 3][1]);      \
  MM(a3, b2, acc[(mb) + 3][2]); MM(a3, b3, acc[(mb) + 3][3]);      \
  __builtin_amdgcn_s_setprio(0);

#define BARF()                                                     \
  { asm volatile("" ::: "memory");                                 \
    __builtin_amdgcn_s_barrier();                                  \
    asm volatile("" ::: "memory"); }
#define LGKM0() asm volatile("s_waitcnt lgkmcnt(0)" ::: "memory");

  // prologue: tile0 full (buf0) + tile1 kh0 (buf1); vmcnt(4) -> tile0 landed.
  STG(A, 0, 0, 0) STG(B, 0, 0, 0) STG(A, 0, 1, 0) STG(B, 0, 1, 0)
  STG(A, 1, 0, 64) STG(B, 1, 0, 64)
  asm volatile("s_waitcnt vmcnt(4)" ::: "memory");
  __builtin_amdgcn_s_barrier();
  asm volatile("" ::: "memory");

  for (int t = 0; t < NT; ++t) {
    const int cur = t & 1, nx = cur ^ 1;
    const int k1 = (t + 1) << 6, k2 = (t + 2) << 6;
    const bool pre1 = (t + 1 < NT), pre2 = (t + 2 < NT);
    // P1: kk0, mh0 — stage A-kh1(t+1) -> buf nx
    LDB4(0) LDA4(0, 0)
    if (pre1) STG(A, nx, 1, k1)
    BARF() LGKM0()
    MFMA16(0)
    BARF()
    // P2: kk0, mh1 — stage B-kh1(t+1) -> buf nx
    LDA4(0, 1)
    if (pre1) STG(B, nx, 1, k1)
    BARF() LGKM0()
    MFMA16(4)
    BARF()
    // P3: kk1, mh0 — stage A-kh0(t+2) -> buf cur (kh0 reads done at P2 bar)
    LDB4(1) LDA4(1, 0)
    if (pre2) STG(A, cur, 0, k2)
    BARF() LGKM0()
    MFMA16(0)
    BARF()
    // P4: kk1, mh1 — stage B-kh0(t+2) -> buf cur; gate
    LDA4(1, 1)
    if (pre2) STG(B, cur, 0, k2)
    BARF() LGKM0()
    MFMA16(4)
    if (pre2)      { asm volatile("s_waitcnt vmcnt(4)" ::: "memory"); }
    else if (pre1) { asm volatile("s_waitcnt vmcnt(0)" ::: "memory"); }
    BARF()
  }
#undef STG
#undef LDA4
#undef LDB4
#undef MM
#undef MFMA16
#undef BARF
#undef LGKM0

  // epilogue: D row=(lane>>4)*4+reg, col=lane&15
  const int row0 = bm * 256 + wm * 128 + l4 * 4;
  const int col0 = bn * 256 + wn * 64 + l15;
  if constexpr (EPI == 0) {
    float bv[4];
#pragma unroll
    for (int ni = 0; ni < 4; ++ni) bv[ni] = bias[col0 + ni * 16];
#pragma unroll
    for (int mi = 0; mi < 8; ++mi)
#pragma unroll
      for (int i = 0; i < 4; ++i) {
        size_t r = (size_t)(row0 + mi * 16 + i) * N;
#pragma unroll
        for (int ni = 0; ni < 4; ++ni)
          Cf[r + col0 + ni * 16] = acc[mi][ni][i] + bv[ni];
      }
  } else {
    const int i3 = bn >> 2;                  // 0=q, 1=k, 2=v
    const int h  = ((bn & 3) << 2) + wn;     // global head 0..15
    if (i3 == 0) {
#pragma unroll
      for (int mi = 0; mi < 8; ++mi)
#pragma unroll
        for (int i = 0; i < 4; ++i) {
          const int row = row0 + mi * 16 + i;
          const int bb = row >> 12, uu = (row >> 6) & 63, nn = row & 63;
          u16* op = Qf + ((size_t)((bb * 16 + h) * 64 + uu)) * 4096
                        + nn * 64 + l15;
          float v0 = acc[mi][0][i], v1 = acc[mi][1][i];
          float v2 = acc[mi][2][i], v3 = acc[mi][3][i];
          float mx = fmaxf(fmaxf(v0, v1), fmaxf(v2, v3));
          mx = fmaxf(mx, __shfl_xor(mx, 1));
          mx = fmaxf(mx, __shfl_xor(mx, 2));
          mx = fmaxf(mx, __shfl_xor(mx, 4));
          mx = fmaxf(mx, __shfl_xor(mx, 8));
          float e0 = __expf(v0 - mx), e1 = __expf(v1 - mx);
          float e2 = __expf(v2 - mx), e3 = __expf(v3 - mx);
          float s = e0 + e1 + e2 + e3;
          s += __shfl_xor(s, 1); s += __shfl_xor(s, 2);
          s += __shfl_xor(s, 4); s += __shfl_xor(s, 8);
          float inv = 0.125f / s;  // e^-0.5 = 1/8
          op[0]  = f2bf(e0 * inv); op[16] = f2bf(e1 * inv);
          op[32] = f2bf(e2 * inv); op[48] = f2bf(e3 * inv);
        }
    } else if (i3 == 1) {
      float sk0[4] = {0.f, 0.f, 0.f, 0.f};
      float sk1[4] = {0.f, 0.f, 0.f, 0.f};
#pragma unroll
      for (int mi = 0; mi < 8; ++mi) {
        const int row = row0 + mi * 16;
        const int bb = row >> 12, uu = (row >> 6) & 63, nn = row & 63;
        u16* op = Kt + ((size_t)((bb * 16 + h) * 64 + uu)) * 4096 + nn;
#pragma unroll
        for (int ni = 0; ni < 4; ++ni) {
          float e0 = __expf(acc[mi][ni][0]);
          float e1 = __expf(acc[mi][ni][1]);
          float e2 = __expf(acc[mi][ni][2]);
          float e3 = __expf(acc[mi][ni][3]);
          u16x4 o;
          o.x = f2bf(e0); o.y = f2bf(e1); o.z = f2bf(e2); o.w = f2bf(e3);
          *reinterpret_cast<u16x4*>(op + (ni * 16 + l15) * 64) = o;
          if (mi < 4) sk0[ni] += e0 + e1 + e2 + e3;
          else        sk1[ni] += e0 + e1 + e2 + e3;
        }
      }
#pragma unroll
      for (int ni = 0; ni < 4; ++ni) {
        sk0[ni] += __shfl_xor(sk0[ni], 16); sk0[ni] += __shfl_xor(sk0[ni], 32);
        sk1[ni] += __shfl_xor(sk1[ni], 16); sk1[ni] += __shfl_xor(sk1[ni], 32);
      }
      if (lane < 16) {
        const int nb0 = bm * 256 + wm * 128;
        const size_t bkt0 = (size_t)(((nb0 >> 12) * 16 + h) * 64 + ((nb0 >> 6) & 63));
#pragma unroll
        for (int ni = 0; ni < 4; ++ni) {
          ksum[bkt0 * 64 + ni * 16 + l15]       = sk0[ni];
          ksum[(bkt0 + 1) * 64 + ni * 16 + l15] = sk1[ni];
        }
      }
    } else {
#pragma unroll
      for (int mi = 0; mi < 8; ++mi) {
        const int row = row0 + mi * 16;
        const int bb = row >> 12, uu = (row >> 6) & 63, nn = row & 63;
        u16* op = Vt + ((size_t)((bb * 16 + h) * 64 + uu)) * 4096 + nn;
#pragma unroll
        for (int ni = 0; ni < 4; ++ni) {
          u16x4 o;
          o.x = f2bf(acc[mi][ni][0]); o.y = f2bf(acc[mi][ni][1]);
          o.z = f2bf(acc[mi][ni][2]); o.w = f2bf(acc[mi][ni][3]);
          *reinterpret_cast<u16x4*>(op + (ni * 16 + l15) * 64) = o;
        }
      }
    }
  }
}

// ---- scanctx2 v3: fused K^TV + exclusive ctx scan + ksum exclusive scan ----
__global__ __launch_bounds__(256) void scanctx2(
    const u16* __restrict__ Kt,  // [bkt][d][n] bf16 (exp'd)
    const u16* __restrict__ Vt,  // [bkt][e][n] bf16
    u16* __restrict__ ctxb,      // [bkt][e][d] bf16 (excl-scanned out)
    float* __restrict__ ksum) {  // [bkt][d] f32 (raw in, exclusive out)
  const int bh = blockIdx.x >> 2, ec = blockIdx.x & 3;
  const int tid = threadIdx.x, lane = tid & 63, wave = tid >> 6;
  const int l15 = lane & 15, l4 = lane >> 4;
  __shared__ u16 KtL[2][2][64][72];  // [buf][bkt parity][d][n]
  __shared__ u16 VtL[2][2][16][72];

  const size_t bbase = (size_t)bh * 64 * 4096;
  const int kr0 = tid >> 3, ks = (tid & 7) * 8;
  const int kr1 = 32 + kr0;
  const bool dov = tid < 128;
  const int vr = tid >> 3, vs = (tid & 7) * 8;
  const bool dok = (ec == 0) && (tid < 64);
  float* kp = dok ? (ksum + (size_t)bh * 4096 + tid) : nullptr;

  f32x4 acc = {0.f, 0.f, 0.f, 0.f};
  u16x8 ka0, ka1, kb0, kb1, va = {}, vb = {};
  float kc0 = 0.f, kc1 = 0.f, kn0 = 0.f, kn1 = 0.f, krun = 0.f;

#define GLD(u_, kx0, kx1, vx)                                          \
  { const size_t nb = bbase + (size_t)(u_) * 4096;                     \
    kx0 = *reinterpret_cast<const u16x8*>(Kt + nb + kr0 * 64 + ks);    \
    kx1 = *reinterpret_cast<const u16x8*>(Kt + nb + kr1 * 64 + ks);    \
    if (dov) vx = *reinterpret_cast<const u16x8*>(                     \
        Vt + nb + (ec * 16 + vr) * 64 + vs); }
#define LWR(buf, j, kx0, kx1, vx)                                      \
  { *reinterpret_cast<u16x8*>(&KtL[buf][j][kr0][ks]) = kx0;            \
    *reinterpret_cast<u16x8*>(&KtL[buf][j][kr1][ks]) = kx1;            \
    if (dov) *reinterpret_cast<u16x8*>(&VtL[buf][j][vr][vs]) = vx; }
#define ACC(buf, j)                                                    \
  _Pragma("unroll")                                                    \
  for (int kk = 0; kk < 2; ++kk) {                                     \
    bf16x8 av = *reinterpret_cast<const bf16x8*>(                      \
        &VtL[buf][j][l15][kk * 32 + l4 * 8]);                          \
    bf16x8 bk = *reinterpret_cast<const bf16x8*>(                      \
        &KtL[buf][j][wave * 16 + l15][kk * 32 + l4 * 8]);              \
    acc = __builtin_amdgcn_mfma_f32_16x16x32_bf16(av, bk, acc, 0, 0, 0); }

  GLD(0, ka0, ka1, va) GLD(1, kb0, kb1, vb)
  if (dok) { kc0 = kp[0]; kc1 = kp[64]; }
  LWR(0, 0, ka0, ka1, va) LWR(0, 1, kb0, kb1, vb)
  __syncthreads();

  for (int u = 0; u < 64; u += 2) {
    const int cur = (u >> 1) & 1, nxt = cur ^ 1;
    const bool pre = (u + 2 < 64);
    if (pre) {
      GLD(u + 2, ka0, ka1, va) GLD(u + 3, kb0, kb1, vb)
      if (dok) { kn0 = kp[(size_t)(u + 2) * 64]; kn1 = kp[(size_t)(u + 3) * 64]; }
    }
    if (dok) {
      kp[(size_t)u * 64] = krun;       krun += kc0;
      kp[(size_t)(u + 1) * 64] = krun; krun += kc1;
      kc0 = kn0; kc1 = kn1;
    }
    u16* cb0 = ctxb + bbase + (size_t)u * 4096 + wave * 16 + l15;
#pragma unroll
    for (int i = 0; i < 4; ++i) cb0[(ec * 16 + l4 * 4 + i) * 64] = f2bf(acc[i]);
    ACC(cur, 0)
    u16* cb1 = cb0 + 4096;
#pragma unroll
    for (int i = 0; i < 4; ++i) cb1[(ec * 16 + l4 * 4 + i) * 64] = f2bf(acc[i]);
    ACC(cur, 1)
    if (pre) { LWR(nxt, 0, ka0, ka1, va) LWR(nxt, 1, kb0, kb1, vb) }
    __syncthreads();
  }
#undef GLD
#undef LWR
#undef ACC
}

// -------- apply v2: attn = (q @ ctx_excl) * Dinv -> AT (fused D-dot) --------
__global__ __launch_bounds__(256) void apply(
    const u16* __restrict__ Q, const u16* __restrict__ ctxc,
    const float* __restrict__ kcum, u16* __restrict__ AT) {
  const int bid = blockIdx.x;
  const int u = bid & 63, bh = bid >> 6, b = bh >> 4, h = bh & 15;
  const int tid = threadIdx.x, lane = tid & 63, wave = tid >> 6;
  const int l15 = lane & 15, l4 = lane >> 4;
  __shared__ float kc[64];

  const size_t base = (size_t)bid * 4096;
  if (tid < 64) kc[tid] = kcum[(size_t)bid * 64 + tid];
  __syncthreads();

  bf16x8 aq[2];
  float dpart = 0.f;
#pragma unroll
  for (int kk = 0; kk < 2; ++kk) {
    aq[kk] = *reinterpret_cast<const bf16x8*>(
        Q + base + (wave * 16 + l15) * 64 + kk * 32 + l4 * 8);
    const float* kcp = &kc[kk * 32 + l4 * 8];
#pragma unroll
    for (int j = 0; j < 8; ++j) dpart += (float)aq[kk][j] * kcp[j];
  }
  dpart += __shfl_xor(dpart, 16);
  dpart += __shfl_xor(dpart, 32);
  const float dinv_self = 1.f / fmaxf(dpart, 1e-3f);
  float dv[4];
#pragma unroll
  for (int i = 0; i < 4; ++i) dv[i] = __shfl(dinv_self, l4 * 4 + i);

  f32x4 acc[4] = {};
  const u16* Cu = ctxc + base;
#pragma unroll
  for (int kk = 0; kk < 2; ++kk)
#pragma unroll
    for (int ni = 0; ni < 4; ++ni) {
      bf16x8 bc = *reinterpret_cast<const bf16x8*>(
          Cu + (ni * 16 + l15) * 64 + kk * 32 + l4 * 8);
      acc[ni] = __builtin_amdgcn_mfma_f32_16x16x32_bf16(aq[kk], bc, acc[ni], 0, 0, 0);
    }
  const size_t orow = ((size_t)b * 4096 + u * 64 + wave * 16 + l4 * 4) * 1024 + h * 64;
#pragma unroll
  for (int i = 0; i < 4; ++i) {
#pragma unroll
    for (int ni = 0; ni < 4; ++ni)
      AT[orow + (size_t)i * 1024 + ni * 16 + l15] = f2bf(acc[ni][i] * dv[i]);
  }
}

// ----------------------------------------------------------------------------
extern "C" void kernel_launch(void* const* d_in, const int* in_sizes, int n_in,
                              void* d_out, int out_size, void* d_ws, size_t ws_size,
                              hipStream_t stream) {
  (void)in_sizes; (void)n_in; (void)out_size; (void)ws_size;
  const float* x      = (const float*)d_in[0];
  const float* qkv_w  = (const float*)d_in[1];
  const float* proj_w = (const float*)d_in[2];
  const float* proj_b = (const float*)d_in[3];
  float* out = (float*)d_out;

  char* ws = (char*)d_ws;
  u16* xb    = (u16*)(ws);
  u16* wq    = (u16*)(ws + 33554432);
  u16* wp    = (u16*)(ws + 39845888);
  u16* Qf    = (u16*)(ws + 41943040);
  u16* Kt    = (u16*)(ws + 75497472);
  u16* Vt    = (u16*)(ws + 109051904);
  u16* ctxb  = (u16*)(ws + 142606336);
  float* ksum = (float*)(ws + 176160768);
  u16* AT    = Kt;  // Kt is dead after scanctx2; apply writes AT over it

  cvt_all<<<dim3(10240), dim3(256), 0, stream>>>(x, qkv_w, proj_w, xb, wq, wp);

  gemm256<2><<<dim3(64 * 12), dim3(512), 0, stream>>>(
      xb, wq, nullptr, nullptr, Qf, Kt, Vt, ksum, 3072, 1024, 16);
  scanctx2<<<dim3(256), dim3(256), 0, stream>>>(Kt, Vt, ctxb, ksum);
  apply<<<dim3(4096), dim3(256), 0, stream>>>(Qf, ctxb, ksum, AT);
  gemm256<0><<<dim3(64 * 4), dim3(512), 0, stream>>>(
      AT, wp, proj_b, out, nullptr, nullptr, nullptr, nullptr, 1024, 1024, 16);
}

// Round 15
// 235.110 us; speedup vs baseline: 1.0439x; 1.0439x over previous
//
#include <hip/hip_runtime.h>
#include <stdint.h>

// ---------------------------------------------------------------------------
// Bucketed linear attention, round 14: exact revert to R12 (best verified:
// 235.7us / 234.3us band). R13's 8-phase rebuild regressed (3rd failed
// schedule rewrite) — the R3 2-barrier/tile K-loop stands.
//   ws layout (~177 MB):
//     xb   bf16 x             33,554,432 B @ 0
//     wq   bf16 qkv_w          6,291,456 B @ 33554432
//     wp   bf16 proj_w         2,097,152 B @ 39845888
//     Qf   bf16 [bkt][n][e]   33,554,432 B @ 41943040
//     Kt   bf16 [bkt][d][n]   33,554,432 B @ 75497472   (exp'd; AT reuses)
//     Vt   bf16 [bkt][e][n]   33,554,432 B @ 109051904
//     ctxb bf16 [bkt][e][d]   33,554,432 B @ 142606336  (excl-scanned)
//     ksum f32  [bkt][d]       1,048,576 B @ 176160768  (in-place excl scan)
// ---------------------------------------------------------------------------

typedef unsigned short u16;
typedef unsigned int u32;
typedef u16   u16x4  __attribute__((ext_vector_type(4)));
typedef u16   u16x8  __attribute__((ext_vector_type(8)));
typedef float f32x4  __attribute__((ext_vector_type(4)));
typedef float float4v __attribute__((ext_vector_type(4)));
typedef __bf16 bf16x8 __attribute__((ext_vector_type(8)));

__device__ __forceinline__ u16 f2bf(float f) {
  return __builtin_bit_cast(u16, (__bf16)f);
}
__device__ __forceinline__ float bf2f(u16 h) {
  return (float)__builtin_bit_cast(__bf16, h);
}

__device__ __forceinline__ void stage16(const u16* g, u16* l) {
  __builtin_amdgcn_global_load_lds(
      (const __attribute__((address_space(1))) u32*)g,
      (__attribute__((address_space(3))) u32*)l, 16, 0, 0);
}

// ------------------- fp32 -> bf16 convert (all 3 inputs) --------------------
__global__ __launch_bounds__(256) void cvt_all(
    const float* __restrict__ x, const float* __restrict__ wqf,
    const float* __restrict__ wpf, u16* __restrict__ xb,
    u16* __restrict__ wq, u16* __restrict__ wp) {
  int i = blockIdx.x * 256 + threadIdx.x;
  const float* in; u16* out; int j;
  if (i < 4194304)      { in = x;   out = xb; j = i; }
  else if (i < 4980736) { in = wqf; out = wq; j = i - 4194304; }
  else                  { in = wpf; out = wp; j = i - 4980736; }
  float4v v = reinterpret_cast<const float4v*>(in)[j];
  u16x4 o;
  o.x = f2bf(v.x); o.y = f2bf(v.y); o.z = f2bf(v.z); o.w = f2bf(v.w);
  reinterpret_cast<u16x4*>(out)[j] = o;
}

// ------------------ 256x256 NT bf16 MFMA GEMM (R3 schedule) -----------------
// EPI=0: float C + bias (proj). EPI=2: fused feature maps ->
//   bn 0-3: softmax_e(q)*e^-0.5 -> Qf[bkt][n][e]
//   bn 4-7: exp(k) -> Kt[bkt][d][n] (u16x4) + ksum[bkt][d] (f32 partials)
//   bn 8-11: v     -> Vt[bkt][e][n] (u16x4)
template <int EPI>
__global__ __launch_bounds__(512, 2) void gemm256(
    const u16* __restrict__ A,      // [M][K] bf16
    const u16* __restrict__ B,      // [N][K] bf16
    const float* __restrict__ bias, // [N] (EPI==0)
    float* __restrict__ Cf,         // (EPI==0)
    u16* __restrict__ Qf, u16* __restrict__ Kt, u16* __restrict__ Vt,
    float* __restrict__ ksum,
    int N, int K, int NT) {         // NT = K/64
  __shared__ u16 As[2][2][256][32];
  __shared__ u16 Bs[2][2][256][32];
  const int tid = threadIdx.x, lane = tid & 63, wave = tid >> 6;
  const int wm = wave >> 2, wn = wave & 3;
  const int l15 = lane & 15, l4 = lane >> 4;
  const int ntn = N >> 8;
  const int cpx = gridDim.x >> 3;
  const int bid = (blockIdx.x & 7) * cpx + (blockIdx.x >> 3);
  const int bm = bid / ntn, bn = bid % ntn;

  const int srow = tid >> 2;
  const int gsl8 = ((tid & 3) ^ ((tid >> 3) & 3)) * 8;
  const u16* Ag = A + (size_t)(bm * 256 + srow) * K + gsl8;
  const u16* Bg = B + (size_t)(bn * 256 + srow) * K + gsl8;
  const size_t rj = (size_t)128 * K;
  const int slotr = (l4 ^ ((l15 >> 1) & 3)) * 8;

  f32x4 acc[8][4] = {};
  bf16x8 a0, a1, a2, a3, a4, a5, a6, a7, b0, b1, b2, b3;

#define STG(P, buf, kh, kt)                                        \
  { const u16* g_ = P##g + (kt) + (kh) * 32;                       \
    stage16(g_,      &P##s[buf][kh][wave * 16][0]);                \
    stage16(g_ + rj, &P##s[buf][kh][128 + wave * 16][0]); }

#define LDA(r0_, r1_, r2_, r3_, kk, mh)                                  \
  { const u16* p_ = &As[cur][kk][wm * 128 + (mh) * 64 + l15][0] + slotr; \
    r0_ = *(const bf16x8*)(p_);                                          \
    r1_ = *(const bf16x8*)(p_ + 512);                                    \
    r2_ = *(const bf16x8*)(p_ + 1024);                                   \
    r3_ = *(const bf16x8*)(p_ + 1536); }

#define LDB(kk)                                                    \
  { const u16* p_ = &Bs[cur][kk][wn * 64 + l15][0] + slotr;        \
    b0 = *(const bf16x8*)(p_);                                     \
    b1 = *(const bf16x8*)(p_ + 512);                               \
    b2 = *(const bf16x8*)(p_ + 1024);                              \
    b3 = *(const bf16x8*)(p_ + 1536); }

#define MM(x, y, z) z = __builtin_amdgcn_mfma_f32_16x16x32_bf16(x, y, z, 0, 0, 0)
#define MFMA16(mb, x0, x1, x2, x3)                                 \
  __builtin_amdgcn_s_setprio(1);                                   \
  MM(x0, b0, acc[(mb) + 0][0]); MM(x0, b1, acc[(mb) + 0][1]);      \
  MM(x0, b2, acc[(mb) + 0][2]); MM(x0, b3, acc[(mb) + 0][3]);      \
  MM(x1, b0, acc[(mb) + 1][0]); MM(x1, b1, acc[(mb) + 1][1]);      \
  MM(x1, b2, acc[(mb) + 1][2]); MM(x1, b3, acc[(mb) + 1][3]);      \
  MM(x2, b0, acc[(mb) + 2][0]); MM(x2, b1, acc[(mb) + 2][1]);      \
  MM(x2, b2, acc[(mb) + 2][2]); MM(x2, b3, acc[(mb) + 2][3]);      \
  MM(x3, b0, acc[(mb) + 3][0]); MM(x3, b1, acc[(mb) + 3][1]);      \
  MM(x3, b2, acc[(mb) + 3][2]); MM(x3, b3, acc[(mb) + 3][3]);      \
  __builtin_amdgcn_s_setprio(0);

#define BARF()                                                     \
  { asm volatile("" ::: "memory");                                 \
    __builtin_amdgcn_s_barrier();                                  \
    asm volatile("" ::: "memory"); }

  STG(A, 0, 0, 0) STG(B, 0, 0, 0) STG(A, 0, 1, 0) STG(B, 0, 1, 0)
  asm volatile("s_waitcnt vmcnt(0)" ::: "memory");
  __builtin_amdgcn_s_barrier();
  asm volatile("" ::: "memory");

  for (int t = 0; t < NT; ++t) {
    const int cur = t & 1, nxt = cur ^ 1;
    const int ktn = (t + 1) << 6;
    const bool pre = (t + 1 < NT);
    LDB(0)
    LDA(a0, a1, a2, a3, 0, 0)
    LDA(a4, a5, a6, a7, 0, 1)
    if (pre) STG(A, nxt, 0, ktn)
    MFMA16(0, a0, a1, a2, a3)
    if (pre) STG(B, nxt, 0, ktn)
    MFMA16(4, a4, a5, a6, a7)
    if (pre) { asm volatile("s_waitcnt vmcnt(4)" ::: "memory"); }
    else     { asm volatile("s_waitcnt vmcnt(0)" ::: "memory"); }
    BARF()
    LDB(1)
    LDA(a0, a1, a2, a3, 1, 0)
    LDA(a4, a5, a6, a7, 1, 1)
    if (pre) STG(A, nxt, 1, ktn)
    MFMA16(0, a0, a1, a2, a3)
    if (pre) STG(B, nxt, 1, ktn)
    MFMA16(4, a4, a5, a6, a7)
    if (pre) { asm volatile("s_waitcnt vmcnt(4)" ::: "memory"); }
    BARF()
  }
#undef STG
#undef LDA
#undef LDB
#undef MM
#undef MFMA16
#undef BARF

  // epilogue: D row=(lane>>4)*4+reg, col=lane&15
  const int row0 = bm * 256 + wm * 128 + l4 * 4;
  const int col0 = bn * 256 + wn * 64 + l15;
  if constexpr (EPI == 0) {
    float bv[4];
#pragma unroll
    for (int ni = 0; ni < 4; ++ni) bv[ni] = bias[col0 + ni * 16];
#pragma unroll
    for (int mi = 0; mi < 8; ++mi)
#pragma unroll
      for (int i = 0; i < 4; ++i) {
        size_t r = (size_t)(row0 + mi * 16 + i) * N;
#pragma unroll
        for (int ni = 0; ni < 4; ++ni)
          Cf[r + col0 + ni * 16] = acc[mi][ni][i] + bv[ni];
      }
  } else {
    const int i3 = bn >> 2;                  // 0=q, 1=k, 2=v
    const int h  = ((bn & 3) << 2) + wn;     // global head 0..15
    if (i3 == 0) {
#pragma unroll
      for (int mi = 0; mi < 8; ++mi)
#pragma unroll
        for (int i = 0; i < 4; ++i) {
          const int row = row0 + mi * 16 + i;
          const int bb = row >> 12, uu = (row >> 6) & 63, nn = row & 63;
          u16* op = Qf + ((size_t)((bb * 16 + h) * 64 + uu)) * 4096
                        + nn * 64 + l15;
          float v0 = acc[mi][0][i], v1 = acc[mi][1][i];
          float v2 = acc[mi][2][i], v3 = acc[mi][3][i];
          float mx = fmaxf(fmaxf(v0, v1), fmaxf(v2, v3));
          mx = fmaxf(mx, __shfl_xor(mx, 1));
          mx = fmaxf(mx, __shfl_xor(mx, 2));
          mx = fmaxf(mx, __shfl_xor(mx, 4));
          mx = fmaxf(mx, __shfl_xor(mx, 8));
          float e0 = __expf(v0 - mx), e1 = __expf(v1 - mx);
          float e2 = __expf(v2 - mx), e3 = __expf(v3 - mx);
          float s = e0 + e1 + e2 + e3;
          s += __shfl_xor(s, 1); s += __shfl_xor(s, 2);
          s += __shfl_xor(s, 4); s += __shfl_xor(s, 8);
          float inv = 0.125f / s;  // e^-0.5 = 1/8
          op[0]  = f2bf(e0 * inv); op[16] = f2bf(e1 * inv);
          op[32] = f2bf(e2 * inv); op[48] = f2bf(e3 * inv);
        }
    } else if (i3 == 1) {
      float sk0[4] = {0.f, 0.f, 0.f, 0.f};
      float sk1[4] = {0.f, 0.f, 0.f, 0.f};
#pragma unroll
      for (int mi = 0; mi < 8; ++mi) {
        const int row = row0 + mi * 16;
        const int bb = row >> 12, uu = (row >> 6) & 63, nn = row & 63;
        u16* op = Kt + ((size_t)((bb * 16 + h) * 64 + uu)) * 4096 + nn;
#pragma unroll
        for (int ni = 0; ni < 4; ++ni) {
          float e0 = __expf(acc[mi][ni][0]);
          float e1 = __expf(acc[mi][ni][1]);
          float e2 = __expf(acc[mi][ni][2]);
          float e3 = __expf(acc[mi][ni][3]);
          u16x4 o;
          o.x = f2bf(e0); o.y = f2bf(e1); o.z = f2bf(e2); o.w = f2bf(e3);
          *reinterpret_cast<u16x4*>(op + (ni * 16 + l15) * 64) = o;
          if (mi < 4) sk0[ni] += e0 + e1 + e2 + e3;
          else        sk1[ni] += e0 + e1 + e2 + e3;
        }
      }
#pragma unroll
      for (int ni = 0; ni < 4; ++ni) {
        sk0[ni] += __shfl_xor(sk0[ni], 16); sk0[ni] += __shfl_xor(sk0[ni], 32);
        sk1[ni] += __shfl_xor(sk1[ni], 16); sk1[ni] += __shfl_xor(sk1[ni], 32);
      }
      if (lane < 16) {
        const int nb0 = bm * 256 + wm * 128;
        const size_t bkt0 = (size_t)(((nb0 >> 12) * 16 + h) * 64 + ((nb0 >> 6) & 63));
#pragma unroll
        for (int ni = 0; ni < 4; ++ni) {
          ksum[bkt0 * 64 + ni * 16 + l15]       = sk0[ni];
          ksum[(bkt0 + 1) * 64 + ni * 16 + l15] = sk1[ni];
        }
      }
    } else {
#pragma unroll
      for (int mi = 0; mi < 8; ++mi) {
        const int row = row0 + mi * 16;
        const int bb = row >> 12, uu = (row >> 6) & 63, nn = row & 63;
        u16* op = Vt + ((size_t)((bb * 16 + h) * 64 + uu)) * 4096 + nn;
#pragma unroll
        for (int ni = 0; ni < 4; ++ni) {
          u16x4 o;
          o.x = f2bf(acc[mi][ni][0]); o.y = f2bf(acc[mi][ni][1]);
          o.z = f2bf(acc[mi][ni][2]); o.w = f2bf(acc[mi][ni][3]);
          *reinterpret_cast<u16x4*>(op + (ni * 16 + l15) * 64) = o;
        }
      }
    }
  }
}

// ---- scanctx2 v3: fused K^TV + exclusive ctx scan + ksum exclusive scan ----
__global__ __launch_bounds__(256) void scanctx2(
    const u16* __restrict__ Kt,  // [bkt][d][n] bf16 (exp'd)
    const u16* __restrict__ Vt,  // [bkt][e][n] bf16
    u16* __restrict__ ctxb,      // [bkt][e][d] bf16 (excl-scanned out)
    float* __restrict__ ksum) {  // [bkt][d] f32 (raw in, exclusive out)
  const int bh = blockIdx.x >> 2, ec = blockIdx.x & 3;
  const int tid = threadIdx.x, lane = tid & 63, wave = tid >> 6;
  const int l15 = lane & 15, l4 = lane >> 4;
  __shared__ u16 KtL[2][2][64][72];  // [buf][bkt parity][d][n]
  __shared__ u16 VtL[2][2][16][72];

  const size_t bbase = (size_t)bh * 64 * 4096;
  const int kr0 = tid >> 3, ks = (tid & 7) * 8;
  const int kr1 = 32 + kr0;
  const bool dov = tid < 128;
  const int vr = tid >> 3, vs = (tid & 7) * 8;
  const bool dok = (ec == 0) && (tid < 64);
  float* kp = dok ? (ksum + (size_t)bh * 4096 + tid) : nullptr;

  f32x4 acc = {0.f, 0.f, 0.f, 0.f};
  u16x8 ka0, ka1, kb0, kb1, va = {}, vb = {};
  float kc0 = 0.f, kc1 = 0.f, kn0 = 0.f, kn1 = 0.f, krun = 0.f;

#define GLD(u_, kx0, kx1, vx)                                          \
  { const size_t nb = bbase + (size_t)(u_) * 4096;                     \
    kx0 = *reinterpret_cast<const u16x8*>(Kt + nb + kr0 * 64 + ks);    \
    kx1 = *reinterpret_cast<const u16x8*>(Kt + nb + kr1 * 64 + ks);    \
    if (dov) vx = *reinterpret_cast<const u16x8*>(                     \
        Vt + nb + (ec * 16 + vr) * 64 + vs); }
#define LWR(buf, j, kx0, kx1, vx)                                      \
  { *reinterpret_cast<u16x8*>(&KtL[buf][j][kr0][ks]) = kx0;            \
    *reinterpret_cast<u16x8*>(&KtL[buf][j][kr1][ks]) = kx1;            \
    if (dov) *reinterpret_cast<u16x8*>(&VtL[buf][j][vr][vs]) = vx; }
#define ACC(buf, j)                                                    \
  _Pragma("unroll")                                                    \
  for (int kk = 0; kk < 2; ++kk) {                                     \
    bf16x8 av = *reinterpret_cast<const bf16x8*>(                      \
        &VtL[buf][j][l15][kk * 32 + l4 * 8]);                          \
    bf16x8 bk = *reinterpret_cast<const bf16x8*>(                      \
        &KtL[buf][j][wave * 16 + l15][kk * 32 + l4 * 8]);              \
    acc = __builtin_amdgcn_mfma_f32_16x16x32_bf16(av, bk, acc, 0, 0, 0); }

  GLD(0, ka0, ka1, va) GLD(1, kb0, kb1, vb)
  if (dok) { kc0 = kp[0]; kc1 = kp[64]; }
  LWR(0, 0, ka0, ka1, va) LWR(0, 1, kb0, kb1, vb)
  __syncthreads();

  for (int u = 0; u < 64; u += 2) {
    const int cur = (u >> 1) & 1, nxt = cur ^ 1;
    const bool pre = (u + 2 < 64);
    if (pre) {
      GLD(u + 2, ka0, ka1, va) GLD(u + 3, kb0, kb1, vb)
      if (dok) { kn0 = kp[(size_t)(u + 2) * 64]; kn1 = kp[(size_t)(u + 3) * 64]; }
    }
    if (dok) {
      kp[(size_t)u * 64] = krun;       krun += kc0;
      kp[(size_t)(u + 1) * 64] = krun; krun += kc1;
      kc0 = kn0; kc1 = kn1;
    }
    u16* cb0 = ctxb + bbase + (size_t)u * 4096 + wave * 16 + l15;
#pragma unroll
    for (int i = 0; i < 4; ++i) cb0[(ec * 16 + l4 * 4 + i) * 64] = f2bf(acc[i]);
    ACC(cur, 0)
    u16* cb1 = cb0 + 4096;
#pragma unroll
    for (int i = 0; i < 4; ++i) cb1[(ec * 16 + l4 * 4 + i) * 64] = f2bf(acc[i]);
    ACC(cur, 1)
    if (pre) { LWR(nxt, 0, ka0, ka1, va) LWR(nxt, 1, kb0, kb1, vb) }
    __syncthreads();
  }
#undef GLD
#undef LWR
#undef ACC
}

// -------- apply v2: attn = (q @ ctx_excl) * Dinv -> AT (fused D-dot) --------
__global__ __launch_bounds__(256) void apply(
    const u16* __restrict__ Q, const u16* __restrict__ ctxc,
    const float* __restrict__ kcum, u16* __restrict__ AT) {
  const int bid = blockIdx.x;
  const int u = bid & 63, bh = bid >> 6, b = bh >> 4, h = bh & 15;
  const int tid = threadIdx.x, lane = tid & 63, wave = tid >> 6;
  const int l15 = lane & 15, l4 = lane >> 4;
  __shared__ float kc[64];

  const size_t base = (size_t)bid * 4096;
  if (tid < 64) kc[tid] = kcum[(size_t)bid * 64 + tid];
  __syncthreads();

  bf16x8 aq[2];
  float dpart = 0.f;
#pragma unroll
  for (int kk = 0; kk < 2; ++kk) {
    aq[kk] = *reinterpret_cast<const bf16x8*>(
        Q + base + (wave * 16 + l15) * 64 + kk * 32 + l4 * 8);
    const float* kcp = &kc[kk * 32 + l4 * 8];
#pragma unroll
    for (int j = 0; j < 8; ++j) dpart += (float)aq[kk][j] * kcp[j];
  }
  dpart += __shfl_xor(dpart, 16);
  dpart += __shfl_xor(dpart, 32);
  const float dinv_self = 1.f / fmaxf(dpart, 1e-3f);
  float dv[4];
#pragma unroll
  for (int i = 0; i < 4; ++i) dv[i] = __shfl(dinv_self, l4 * 4 + i);

  f32x4 acc[4] = {};
  const u16* Cu = ctxc + base;
#pragma unroll
  for (int kk = 0; kk < 2; ++kk)
#pragma unroll
    for (int ni = 0; ni < 4; ++ni) {
      bf16x8 bc = *reinterpret_cast<const bf16x8*>(
          Cu + (ni * 16 + l15) * 64 + kk * 32 + l4 * 8);
      acc[ni] = __builtin_amdgcn_mfma_f32_16x16x32_bf16(aq[kk], bc, acc[ni], 0, 0, 0);
    }
  const size_t orow = ((size_t)b * 4096 + u * 64 + wave * 16 + l4 * 4) * 1024 + h * 64;
#pragma unroll
  for (int i = 0; i < 4; ++i) {
#pragma unroll
    for (int ni = 0; ni < 4; ++ni)
      AT[orow + (size_t)i * 1024 + ni * 16 + l15] = f2bf(acc[ni][i] * dv[i]);
  }
}

// ----------------------------------------------------------------------------
extern "C" void kernel_launch(void* const* d_in, const int* in_sizes, int n_in,
                              void* d_out, int out_size, void* d_ws, size_t ws_size,
                              hipStream_t stream) {
  (void)in_sizes; (void)n_in; (void)out_size; (void)ws_size;
  const float* x      = (const float*)d_in[0];
  const float* qkv_w  = (const float*)d_in[1];
  const float* proj_w = (const float*)d_in[2];
  const float* proj_b = (const float*)d_in[3];
  float* out = (float*)d_out;

  char* ws = (char*)d_ws;
  u16* xb    = (u16*)(ws);
  u16* wq    = (u16*)(ws + 33554432);
  u16* wp    = (u16*)(ws + 39845888);
  u16* Qf    = (u16*)(ws + 41943040);
  u16* Kt    = (u16*)(ws + 75497472);
  u16* Vt    = (u16*)(ws + 109051904);
  u16* ctxb  = (u16*)(ws + 142606336);
  float* ksum = (float*)(ws + 176160768);
  u16* AT    = Kt;  // Kt is dead after scanctx2; apply writes AT over it

  cvt_all<<<dim3(20480), dim3(256), 0, stream>>>(x, qkv_w, proj_w, xb, wq, wp);

  gemm256<2><<<dim3(64 * 12), dim3(512), 0, stream>>>(
      xb, wq, nullptr, nullptr, Qf, Kt, Vt, ksum, 3072, 1024, 16);
  scanctx2<<<dim3(256), dim3(256), 0, stream>>>(Kt, Vt, ctxb, ksum);
  apply<<<dim3(4096), dim3(256), 0, stream>>>(Qf, ctxb, ksum, AT);
  gemm256<0><<<dim3(64 * 4), dim3(512), 0, stream>>>(
      AT, wp, proj_b, out, nullptr, nullptr, nullptr, nullptr, 1024, 1024, 16);
}